// Round 7
// baseline (32.519 us; speedup 1.0000x reference)
//
#include <hip/hip_runtime.h>

// Problem constants (fixed by reference setup_inputs)
constexpr int B_ = 32;
constexpr int S_ = 4096;
constexpr int D_ = 256;
constexpr int PAIRS_PER_BATCH = S_ - 1;                                   // 4095
constexpr int CHUNK = 16;                                                 // pairs per wave
constexpr int CHUNKS_PER_BATCH = (PAIRS_PER_BATCH + CHUNK - 1) / CHUNK;   // 256
constexpr int TOTAL_WAVES = B_ * CHUNKS_PER_BATCH;                        // 8192
constexpr int BLOCK = 256;
constexpr int WAVES_PER_BLOCK = BLOCK / 64;                               // 4
constexpr int GRID1 = TOTAL_WAVES / WAVES_PER_BLOCK;                      // 2048
constexpr int GROUP_SIZE = 64;                                            // blocks per group
constexpr int NGROUPS = GRID1 / GROUP_SIZE;                               // 32

// Workspace layout (zeroed by a memset node at the head of every call):
//   u64 grp_acc[NGROUPS]   @ 0      fixed-point group accumulators
//   u64 glb_acc            @ 256
//   u32 grp_cnt[NGROUPS]   @ 264    completion counters (exact: start at 0)
//   u32 glb_cnt            @ 392
constexpr size_t WS_ZERO_BYTES = 512;

// Single compute kernel. Cross-block reduction via fixed-point (x 2^24)
// int64 atomic adds -> exactly associative -> bit-identical output every
// call. Completion counters start at 0 each call (memset node), so the
// finisher detection (o1==GROUP_SIZE-1, o2==NGROUPS-1) fires only after ALL
// contributions at that level completed (each thread's counter-add is issued
// only after its value-add's return was consumed -> value RMW performed at
// the coherence point first). Accumulator reads are opaque-zero atomicAdds
// (inline-asm-laundered 0) so the compiler cannot relax the RMW to a plain
// atomic load; same-address RMWs serialize at one coherence point.
__global__ __launch_bounds__(BLOCK) void ccl_fused_kernel(
    const float* __restrict__ emb,
    const int* __restrict__ lab,
    float* __restrict__ out,
    unsigned long long* __restrict__ grp_acc,   // NGROUPS
    unsigned long long* __restrict__ glb_acc,   // 1
    unsigned int* __restrict__ grp_cnt,         // NGROUPS
    unsigned int* __restrict__ glb_cnt) {       // 1
  const int tid = threadIdx.x;
  const int lane = tid & 63;
  const int w = tid >> 6;
  const int wave = blockIdx.x * WAVES_PER_BLOCK + w;

  const int b = wave / CHUNKS_PER_BATCH;
  const int c = wave % CHUNKS_PER_BATCH;
  const int p0 = c * CHUNK;
  const int npairs = min(CHUNK, PAIRS_PER_BATCH - p0);   // 16 (15 for last chunk)

  const float4* __restrict__ rows =
      reinterpret_cast<const float4*>(emb + (size_t)b * S_ * D_);
  const int* __restrict__ lb = lab + b * S_;

  // --- Phase A: pair mask via ballot (one coalesced label read per wave) ---
  float wsum = 0.0f;
  int lv = 0;
  if (lane <= npairs) lv = lb[p0 + lane];
  const int nl = __shfl_down(lv, 1, 64);
  const bool m = (lane < npairs) && (lv != 0) && (lv == nl);
  const unsigned long long mask = __ballot(m);

  if (mask != 0ULL) {
    const unsigned long long rowmask = mask | (mask << 1);

    // --- Phase B: needed row loads (conditional; proven layout from R2) ---
    float4 r[CHUNK + 1];
    #pragma unroll
    for (int i = 0; i <= CHUNK; ++i) {
      if ((rowmask >> i) & 1ULL) {
        r[i] = rows[(size_t)(p0 + i) * (D_ / 4) + lane];
      }
    }

    // --- Phase C: reduce each masked pair ---
    #pragma unroll
    for (int i = 0; i < CHUNK; ++i) {
      if ((mask >> i) & 1ULL) {
        const float dx = r[i].x - r[i + 1].x;
        const float dy = r[i].y - r[i + 1].y;
        const float dz = r[i].z - r[i + 1].z;
        const float dw = r[i].w - r[i + 1].w;
        float s = dx * dx + dy * dy + dz * dz + dw * dw;
        #pragma unroll
        for (int xm = 1; xm < 64; xm <<= 1) s += __shfl_xor(s, xm, 64);
        wsum += sqrtf(s);
      }
    }
  }

  // --- Block partial (fixed order across the 4 waves) ---
  __shared__ float lds[WAVES_PER_BLOCK];
  if (lane == 0) lds[w] = wsum;
  __syncthreads();
  if (tid != 0) return;

  float bsum = 0.0f;
  #pragma unroll
  for (int i = 0; i < WAVES_PER_BLOCK; ++i) bsum += lds[i];

  // Fixed-point contribution (exact-associative integer accumulation).
  const long long fx = (long long)llrintf(bsum * 16777216.0f);   // * 2^24
  const int g = blockIdx.x / GROUP_SIZE;

  unsigned long long r1 = atomicAdd(&grp_acc[g], (unsigned long long)fx);
  asm volatile("" ::"v"(r1));                 // value RMW completed before...
  const unsigned int o1 = atomicAdd(&grp_cnt[g], 1u);   // ...counter RMW
  if (o1 == GROUP_SIZE - 1) {                 // exact: counters zeroed per call
    unsigned long long z1 = 0;
    asm volatile("" : "+v"(z1));              // opaque zero -> stays an RMW
    const unsigned long long gt = atomicAdd(&grp_acc[g], z1);  // full group sum
    unsigned long long r2 = atomicAdd(glb_acc, gt);
    asm volatile("" ::"v"(r2));
    const unsigned int o2 = atomicAdd(glb_cnt, 1u);
    if (o2 == NGROUPS - 1) {                  // unique, truly-last finisher
      unsigned long long z2 = 0;
      asm volatile("" : "+v"(z2));
      const unsigned long long total = atomicAdd(glb_acc, z2);
      const double loss = (double)(long long)total /
                          (16777216.0 * (double)((long long)B_ * S_));
      out[0] = (float)loss;
    }
  }
}

extern "C" void kernel_launch(void* const* d_in, const int* in_sizes, int n_in,
                              void* d_out, int out_size, void* d_ws, size_t ws_size,
                              hipStream_t stream) {
  const float* emb = (const float*)d_in[0];
  const int* lab = (const int*)d_in[1];
  float* out = (float*)d_out;

  char* ws = (char*)d_ws;
  unsigned long long* grp_acc = (unsigned long long*)ws;            // @0
  unsigned long long* glb_acc = (unsigned long long*)(ws + 256);    // @256
  unsigned int* grp_cnt = (unsigned int*)(ws + 264);                // @264
  unsigned int* glb_cnt = (unsigned int*)(ws + 392);                // @392

  // Node 1: zero counters/accumulators (512 B). Independent of inputs,
  // ordered before the compute kernel by stream order. Graph-capturable.
  hipMemsetAsync(d_ws, 0, WS_ZERO_BYTES, stream);

  // Node 2: fused compute + reduction.
  ccl_fused_kernel<<<GRID1, BLOCK, 0, stream>>>(emb, lab, out, grp_acc,
                                                glb_acc, grp_cnt, glb_cnt);
}

// Round 9
// 15.564 us; speedup vs baseline: 2.0894x; 2.0894x over previous
//
#include <hip/hip_runtime.h>
#include <hip/hip_cooperative_groups.h>

namespace cg = cooperative_groups;

// Problem constants (fixed by reference setup_inputs)
constexpr int B_ = 32;
constexpr int S_ = 4096;
constexpr int D_ = 256;
constexpr int PAIRS_PER_BATCH = S_ - 1;                                   // 4095
constexpr int CHUNK = 16;                                                 // pairs per chunk
constexpr int CHUNKS_PER_BATCH = (PAIRS_PER_BATCH + CHUNK - 1) / CHUNK;   // 256
constexpr int NCHUNKS = B_ * CHUNKS_PER_BATCH;                            // 8192
constexpr int BLOCK = 256;
constexpr int WAVES_PER_BLOCK = BLOCK / 64;                               // 4
constexpr int NBLOCKS = 1024;                                             // 4 blocks/CU needed
constexpr int NWAVES = NBLOCKS * WAVES_PER_BLOCK;                         // 4096 (2 chunks/wave)

// One chunk (16 consecutive pairs of one batch row): ballot mask from one
// coalesced label read; row loads gated by the mask (only rows adjacent to
// a masked pair); per-pair diff + 64-lane butterfly + sqrt. Returns the
// wave-uniform partial sum. All branches are wave-uniform.
__device__ __forceinline__ float chunk_sum(const float* __restrict__ emb,
                                           const int* __restrict__ lab,
                                           int chunk, int lane) {
  const int b = chunk / CHUNKS_PER_BATCH;
  const int c = chunk % CHUNKS_PER_BATCH;
  const int p0 = c * CHUNK;
  const int npairs = min(CHUNK, PAIRS_PER_BATCH - p0);   // 16 (15 for last chunk)

  const float4* __restrict__ rows =
      reinterpret_cast<const float4*>(emb + (size_t)b * S_ * D_);
  const int* __restrict__ lb = lab + b * S_;

  int lv = 0;
  if (lane <= npairs) lv = lb[p0 + lane];
  const int nl = __shfl_down(lv, 1, 64);
  const bool m = (lane < npairs) && (lv != 0) && (lv == nl);
  const unsigned long long mask = __ballot(m);
  if (mask == 0ULL) return 0.0f;

  const unsigned long long rowmask = mask | (mask << 1);

  float4 r[CHUNK + 1];
  #pragma unroll
  for (int i = 0; i <= CHUNK; ++i) {
    if ((rowmask >> i) & 1ULL) {
      r[i] = rows[(size_t)(p0 + i) * (D_ / 4) + lane];
    }
  }

  float wsum = 0.0f;
  #pragma unroll
  for (int i = 0; i < CHUNK; ++i) {
    if ((mask >> i) & 1ULL) {
      const float dx = r[i].x - r[i + 1].x;
      const float dy = r[i].y - r[i + 1].y;
      const float dz = r[i].z - r[i + 1].z;
      const float dw = r[i].w - r[i + 1].w;
      float s = dx * dx + dy * dy + dz * dz + dw * dw;
      #pragma unroll
      for (int xm = 1; xm < 64; xm <<= 1) s += __shfl_xor(s, xm, 64);
      wsum += sqrtf(s);
    }
  }
  return wsum;
}

// Block-level: each wave sums its 2 chunks; 4 wave partials -> block partial.
__device__ __forceinline__ void block_partial(const float* __restrict__ emb,
                                              const int* __restrict__ lab,
                                              float* __restrict__ partial) {
  const int tid = threadIdx.x;
  const int lane = tid & 63;
  const int w = tid >> 6;
  const int wave = blockIdx.x * WAVES_PER_BLOCK + w;

  float wsum = 0.0f;
  #pragma unroll
  for (int ci = wave; ci < NCHUNKS; ci += NWAVES) {   // exactly 2 iterations
    wsum += chunk_sum(emb, lab, ci, lane);
  }

  __shared__ float lds[WAVES_PER_BLOCK];
  if (lane == 0) lds[w] = wsum;
  __syncthreads();
  if (tid == 0) {
    partial[blockIdx.x] = ((lds[0] + lds[1]) + lds[2]) + lds[3];
  }
}

// Cooperative single-node version: grid.sync then block 0 reduces.
__global__ __launch_bounds__(BLOCK, 4) void ccl_coop_kernel(
    const float* __restrict__ emb, const int* __restrict__ lab,
    float* __restrict__ out, float* __restrict__ partial) {
  block_partial(emb, lab, partial);

  cg::this_grid().sync();

  if (blockIdx.x != 0) return;
  const int tid = threadIdx.x;
  const int lane = tid & 63;
  const int w = tid >> 6;
  float s = 0.0f;
  for (int i = tid; i < NBLOCKS; i += BLOCK) s += partial[i];   // 4 each, fixed order
  #pragma unroll
  for (int xm = 1; xm < 64; xm <<= 1) s += __shfl_xor(s, xm, 64);
  __shared__ float lds2[WAVES_PER_BLOCK];
  if (lane == 0) lds2[w] = s;
  __syncthreads();
  if (tid == 0) {
    out[0] = (((lds2[0] + lds2[1]) + lds2[2]) + lds2[3]) /
             (float)((long long)B_ * S_);
  }
}

// Fallback two-kernel version (proven structure, 22.4 us baseline).
__global__ __launch_bounds__(BLOCK, 4) void ccl_body_kernel(
    const float* __restrict__ emb, const int* __restrict__ lab,
    float* __restrict__ partial) {
  block_partial(emb, lab, partial);
}

__global__ __launch_bounds__(BLOCK) void ccl_reduce_kernel(
    const float* __restrict__ partial, float* __restrict__ out) {
  const int tid = threadIdx.x;
  const int lane = tid & 63;
  const int w = tid >> 6;
  float s = 0.0f;
  for (int i = tid; i < NBLOCKS; i += BLOCK) s += partial[i];
  #pragma unroll
  for (int xm = 1; xm < 64; xm <<= 1) s += __shfl_xor(s, xm, 64);
  __shared__ float lds2[WAVES_PER_BLOCK];
  if (lane == 0) lds2[w] = s;
  __syncthreads();
  if (tid == 0) {
    out[0] = (((lds2[0] + lds2[1]) + lds2[2]) + lds2[3]) /
             (float)((long long)B_ * S_);
  }
}

extern "C" void kernel_launch(void* const* d_in, const int* in_sizes, int n_in,
                              void* d_out, int out_size, void* d_ws, size_t ws_size,
                              hipStream_t stream) {
  const float* emb = (const float*)d_in[0];
  const int* lab = (const int*)d_in[1];
  float* out = (float*)d_out;
  float* partial = (float*)d_ws;   // NBLOCKS floats = 4 KiB

  // Host-side, capture-safe, deterministic gating: only take the cooperative
  // path if the runtime confirms full co-residency for this grid.
  int dev = 0;
  (void)hipGetDevice(&dev);
  int coop = 0;
  (void)hipDeviceGetAttribute(&coop, hipDeviceAttributeCooperativeLaunch, dev);
  int ncu = 0;
  (void)hipDeviceGetAttribute(&ncu, hipDeviceAttributeMultiprocessorCount, dev);
  int maxb = 0;
  (void)hipOccupancyMaxActiveBlocksPerMultiprocessor(
      &maxb, (const void*)ccl_coop_kernel, BLOCK, 0);

  if (coop && (long long)maxb * ncu >= NBLOCKS) {
    void* args[4] = {(void*)&emb, (void*)&lab, (void*)&out, (void*)&partial};
    hipError_t e = hipLaunchCooperativeKernel((const void*)ccl_coop_kernel,
                                              dim3(NBLOCKS), dim3(BLOCK), args,
                                              0, stream);
    if (e == hipSuccess) return;
    // else fall through to the two-kernel path
  }

  ccl_body_kernel<<<NBLOCKS, BLOCK, 0, stream>>>(emb, lab, partial);
  ccl_reduce_kernel<<<1, BLOCK, 0, stream>>>(partial, out);
}